// Round 2
// baseline (241.058 us; speedup 1.0000x reference)
//
#include <hip/hip_runtime.h>

// SkipGram negative-sampling loss on MI355X — round 2.
// One wave per batch element. 8-lane groups x 8 labels per chunk,
// indices preloaded into registers (no dependent index loads in the loop),
// depth-2 software pipeline on row loads, logsig applied full-wave-wide.

#define VOCAB  100000
#define EMB    128
#define B_TOT  16384
#define W_POS  10
#define K_NEG  64
#define N_LAB  (W_POS + K_NEG)   // 74

__device__ __forceinline__ float logsig(float x) {
    // jax.nn.log_sigmoid: min(x,0) - log1p(exp(-|x|))
    return fminf(x, 0.0f) - log1pf(__expf(-fabsf(x)));
}

__global__ __launch_bounds__(256) void skipgram_kernel(
    const int*   __restrict__ input,       // [B]
    const int*   __restrict__ pos_labels,  // [B, W_POS]
    const int*   __restrict__ neg_labels,  // [B, K_NEG]
    const float* __restrict__ input_emb,   // [VOCAB, EMB]
    const float* __restrict__ output_emb,  // [VOCAB, EMB]
    float*       __restrict__ out)         // [1]
{
    const int lane = threadIdx.x & 63;
    const int gl   = lane & 7;    // lane within 8-lane group
    const int wave   = (int)((blockIdx.x * blockDim.x + threadIdx.x) >> 6);
    const int nwaves = (int)((gridDim.x * blockDim.x) >> 6);

    float acc = 0.0f;

    for (int b = wave; b < B_TOT; b += nwaves) {
        const int c = input[b];
        const int* pl = pos_labels + b * W_POS;
        const int* nl = neg_labels + b * K_NEG;

        // Preload all 74 indices into 2 regs/lane (label j on lane j / j-64).
        int idx0 = (lane < W_POS) ? pl[lane] : nl[lane - W_POS];     // j = lane
        int idx1 = nl[(lane < 10) ? (54 + lane) : 63];               // j = 64+lane (lanes 0..9)

        // Center row, interleaved layout: lane's k-th float4 = crow4[k*8+gl]
        const float4* crow = (const float4*)(input_emb + (size_t)c * EMB);
        const float4 c0 = crow[gl], c1 = crow[8 + gl],
                     c2 = crow[16 + gl], c3 = crow[24 + gl];

        float d0 = 0.0f, d1 = 0.0f;  // per-lane dot slots (labels lane / 64+lane)

        // Prologue: chunk 0 rows (labels 0..7, group g handles label g).
        int r0 = __shfl(idx0, lane >> 3);
        const float4* rp = (const float4*)(output_emb + (size_t)r0 * EMB);
        float4 a0 = rp[gl], a1 = rp[8 + gl], a2 = rp[16 + gl], a3 = rp[24 + gl];

        #pragma unroll
        for (int t = 0; t < 10; ++t) {
            // Prefetch next chunk's rows (depth-2 pipeline).
            float4 n0, n1, n2, n3;
            if (t < 9) {
                const int tn = t + 1;
                int rn = (tn < 8) ? __shfl(idx0, 8 * tn + (lane >> 3))
                                  : __shfl(idx1, 8 * (tn - 8) + (lane >> 3));
                const float4* np = (const float4*)(output_emb + (size_t)rn * EMB);
                n0 = np[gl]; n1 = np[8 + gl]; n2 = np[16 + gl]; n3 = np[24 + gl];
            }

            // 128-dim dot, 16 lanes... 8 lanes x 16 dims each (interleaved).
            float p = a0.x * c0.x + a0.y * c0.y + a0.z * c0.z + a0.w * c0.w
                    + a1.x * c1.x + a1.y * c1.y + a1.z * c1.z + a1.w * c1.w
                    + a2.x * c2.x + a2.y * c2.y + a2.z * c2.z + a2.w * c2.w
                    + a3.x * c3.x + a3.y * c3.y + a3.z * c3.z + a3.w * c3.w;

            // In-group butterfly: all 8 lanes of the group get the full dot.
            p += __shfl_xor(p, 1);
            p += __shfl_xor(p, 2);
            p += __shfl_xor(p, 4);

            // Transpose: lane l grabs group (l&7)'s dot; keeps it if its
            // label (l or 64+l) belongs to this chunk.
            const float v = __shfl(p, (lane & 7) << 3);
            if (t < 8) { if ((lane >> 3) == t)     d0 = v; }
            else       { if ((lane >> 3) == t - 8) d1 = v; }

            a0 = n0; a1 = n1; a2 = n2; a3 = n3;
        }

        // Full-wave-wide logsigmoid: 2 passes instead of 19 sparse ones.
        acc += logsig(d0);                    // labels 0..63, all lanes valid
        if (lane < 10) acc += logsig(d1);     // labels 64..73
    }

    // Wave reduction -> lane 0.
    acc += __shfl_xor(acc, 1);
    acc += __shfl_xor(acc, 2);
    acc += __shfl_xor(acc, 4);
    acc += __shfl_xor(acc, 8);
    acc += __shfl_xor(acc, 16);
    acc += __shfl_xor(acc, 32);

    if (lane == 0) atomicAdd(out, -acc);
}

extern "C" void kernel_launch(void* const* d_in, const int* in_sizes, int n_in,
                              void* d_out, int out_size, void* d_ws, size_t ws_size,
                              hipStream_t stream) {
    const int*   input      = (const int*)  d_in[0];
    const int*   pos_labels = (const int*)  d_in[1];
    const int*   neg_labels = (const int*)  d_in[2];
    const float* input_emb  = (const float*)d_in[3];
    const float* output_emb = (const float*)d_in[4];
    float*       out        = (float*)      d_out;

    // d_out is poisoned (0xAA) and not re-zeroed between replays.
    hipMemsetAsync(out, 0, sizeof(float), stream);

    // 4096 blocks x 256 threads = 16384 waves -> 1 batch element per wave.
    dim3 grid(4096), block(256);
    hipLaunchKernelGGL(skipgram_kernel, grid, block, 0, stream,
                       input, pos_labels, neg_labels, input_emb, output_emb, out);
}

// Round 3
// 182.345 us; speedup vs baseline: 1.3220x; 1.3220x over previous
//
#include <hip/hip_runtime.h>

// SkipGram negative-sampling loss on MI355X — round 3.
// R1 structure (16-lane groups, 4 labels/chunk, constant-mask swizzle
// reductions) + (a) hardware-instruction logsigmoid instead of libm log1pf,
// (b) two independent batch elements interleaved per wave for 2x MLP.

#define VOCAB  100000
#define EMB    128
#define B_TOT  16384
#define W_POS  10
#define K_NEG  64
#define N_LAB  (W_POS + K_NEG)   // 74

__device__ __forceinline__ float logsig(float x) {
    // log_sigmoid(x) = min(x,0) - log1p(exp(-|x|))
    // log1p(e) with e in (0,1]: log2(1+e)*ln2 via v_exp_f32/v_log_f32.
    const float e = __expf(-fabsf(x));          // v_mul + v_exp_f32
    return fminf(x, 0.0f) - 0.69314718056f * __log2f(1.0f + e);
}

__global__ __launch_bounds__(256) void skipgram_kernel(
    const int*   __restrict__ input,       // [B]
    const int*   __restrict__ pos_labels,  // [B, W_POS]
    const int*   __restrict__ neg_labels,  // [B, K_NEG]
    const float* __restrict__ input_emb,   // [VOCAB, EMB]
    const float* __restrict__ output_emb,  // [VOCAB, EMB]
    float*       __restrict__ out)         // [1]
{
    const int lane = threadIdx.x & 63;
    const int gl   = lane & 15;   // lane within 16-lane group
    const int grp  = lane >> 4;   // group id: which label of the chunk
    const int wave = (int)((blockIdx.x * blockDim.x + threadIdx.x) >> 6);

    // Two independent elements per wave (adjacent -> label-array locality).
    const int e0 = wave * 2;
    const int e1 = wave * 2 + 1;

    const int c0i = input[e0];
    const int c1i = input[e1];
    const float4* c0p = (const float4*)(input_emb + (size_t)c0i * EMB);
    const float4* c1p = (const float4*)(input_emb + (size_t)c1i * EMB);
    const float4 c00 = c0p[gl * 2], c01 = c0p[gl * 2 + 1];
    const float4 c10 = c1p[gl * 2], c11 = c1p[gl * 2 + 1];

    const int* pl0 = pos_labels + e0 * W_POS;
    const int* nl0 = neg_labels + e0 * K_NEG;
    const int* pl1 = pos_labels + e1 * W_POS;
    const int* nl1 = neg_labels + e1 * K_NEG;

    float acc = 0.0f;

    for (int t = 0; t < 19; ++t) {
        const int  j     = t * 4 + grp;
        const bool valid = (j < N_LAB);

        int r0 = 0, r1 = 0;
        if (valid) {
            r0 = (j < W_POS) ? pl0[j] : nl0[j - W_POS];
            r1 = (j < W_POS) ? pl1[j] : nl1[j - W_POS];
        }

        // Both elements' rows issued back-to-back: 4 dwordx4 in flight.
        const float4* rp0 = (const float4*)(output_emb + (size_t)r0 * EMB);
        const float4* rp1 = (const float4*)(output_emb + (size_t)r1 * EMB);
        const float4 a0 = rp0[gl * 2], a1 = rp0[gl * 2 + 1];
        const float4 b0 = rp1[gl * 2], b1 = rp1[gl * 2 + 1];

        float p = a0.x * c00.x + a0.y * c00.y + a0.z * c00.z + a0.w * c00.w
                + a1.x * c01.x + a1.y * c01.y + a1.z * c01.z + a1.w * c01.w;
        float q = b0.x * c10.x + b0.y * c10.y + b0.z * c10.z + b0.w * c10.w
                + b1.x * c11.x + b1.y * c11.y + b1.z * c11.z + b1.w * c11.w;

        // Constant-mask butterflies (ds_swizzle, conflict-free); the two
        // chains are independent and overlap.
        p += __shfl_xor(p, 1);  q += __shfl_xor(q, 1);
        p += __shfl_xor(p, 2);  q += __shfl_xor(q, 2);
        p += __shfl_xor(p, 4);  q += __shfl_xor(q, 4);
        p += __shfl_xor(p, 8);  q += __shfl_xor(q, 8);

        if (valid && gl == 0) acc += logsig(p) + logsig(q);
    }

    // Combine group accumulators (lanes 0,16,32,48) -> lane 0.
    acc += __shfl_xor(acc, 16);
    acc += __shfl_xor(acc, 32);

    if (lane == 0) atomicAdd(out, -acc);
}

extern "C" void kernel_launch(void* const* d_in, const int* in_sizes, int n_in,
                              void* d_out, int out_size, void* d_ws, size_t ws_size,
                              hipStream_t stream) {
    const int*   input      = (const int*)  d_in[0];
    const int*   pos_labels = (const int*)  d_in[1];
    const int*   neg_labels = (const int*)  d_in[2];
    const float* input_emb  = (const float*)d_in[3];
    const float* output_emb = (const float*)d_in[4];
    float*       out        = (float*)      d_out;

    // d_out is poisoned (0xAA) and not re-zeroed between replays.
    hipMemsetAsync(out, 0, sizeof(float), stream);

    // 2048 blocks x 256 threads = 8192 waves x 2 elements each.
    dim3 grid(2048), block(256);
    hipLaunchKernelGGL(skipgram_kernel, grid, block, 0, stream,
                       input, pos_labels, neg_labels, input_emb, output_emb, out);
}

// Round 4
// 98.700 us; speedup vs baseline: 2.4423x; 1.8475x over previous
//
#include <hip/hip_runtime.h>

// SkipGram negative-sampling loss on MI355X — round 4.
// Latency-bound fix: maximize memory-level parallelism per wave.
//  - all 19 label-index loads hoisted & in flight up front
//  - depth-4 explicit software pipeline on row loads (fully unrolled,
//    static slot indexing only)
//  - __launch_bounds__(256,4) -> VGPR cap ~128 so the pipeline fits
//  - one element per wave; block-level LDS reduce -> 1 atomic/block

#define VOCAB  100000
#define EMB    128
#define B_TOT  16384
#define W_POS  10
#define K_NEG  64
#define N_LAB  (W_POS + K_NEG)   // 74
#define NCHUNK 19                // ceil(74/4)
#define DEPTH  4                 // row-load pipeline depth

__device__ __forceinline__ float logsig(float x) {
    // log_sigmoid(x) = min(x,0) - log1p(exp(-|x|)); hw exp/log only.
    const float e = __expf(-fabsf(x));
    return fminf(x, 0.0f) - 0.69314718056f * __log2f(1.0f + e);
}

__global__ __launch_bounds__(256, 4) void skipgram_kernel(
    const int*   __restrict__ input,       // [B]
    const int*   __restrict__ pos_labels,  // [B, W_POS]
    const int*   __restrict__ neg_labels,  // [B, K_NEG]
    const float* __restrict__ input_emb,   // [VOCAB, EMB]
    const float* __restrict__ output_emb,  // [VOCAB, EMB]
    float*       __restrict__ out)         // [1]
{
    const int lane = threadIdx.x & 63;
    const int gl   = lane & 15;   // lane within 16-lane group
    const int grp  = lane >> 4;   // which label of each 4-label chunk
    const int wave = (int)((blockIdx.x * blockDim.x + threadIdx.x) >> 6);
    const int b    = wave;        // one element per wave, grid sized exactly

    const int* pl = pos_labels + b * W_POS;
    const int* nl = neg_labels + b * K_NEG;

    // ---- all index loads up front (independent, all in flight) ----
    int idx[NCHUNK];
    #pragma unroll
    for (int t = 0; t < NCHUNK; ++t) {
        const int j = 4 * t + grp;
        idx[t] = (j < W_POS) ? pl[j] : ((j < N_LAB) ? nl[j - W_POS] : 0);
    }

    // ---- center row ----
    const int c = input[b];
    const float4* crow = (const float4*)(input_emb + (size_t)c * EMB);
    const float4 c0 = crow[gl * 2], c1 = crow[gl * 2 + 1];

    // ---- depth-4 pipelined row gathers ----
    float4 A[DEPTH][2];
    #pragma unroll
    for (int t = 0; t < DEPTH; ++t) {
        const float4* rp = (const float4*)(output_emb + (size_t)idx[t] * EMB);
        A[t][0] = rp[gl * 2];
        A[t][1] = rp[gl * 2 + 1];
    }

    float acc = 0.0f;

    #pragma unroll
    for (int t = 0; t < NCHUNK; ++t) {
        const float4 a0 = A[t % DEPTH][0];
        const float4 a1 = A[t % DEPTH][1];

        // refill this slot with chunk t+DEPTH (static index after unroll)
        if (t + DEPTH < NCHUNK) {
            const float4* rp =
                (const float4*)(output_emb + (size_t)idx[t + DEPTH] * EMB);
            A[t % DEPTH][0] = rp[gl * 2];
            A[t % DEPTH][1] = rp[gl * 2 + 1];
        }

        float p = a0.x * c0.x + a0.y * c0.y + a0.z * c0.z + a0.w * c0.w
                + a1.x * c1.x + a1.y * c1.y + a1.z * c1.z + a1.w * c1.w;

        p += __shfl_xor(p, 1);
        p += __shfl_xor(p, 2);
        p += __shfl_xor(p, 4);
        p += __shfl_xor(p, 8);

        const int j = 4 * t + grp;
        if (gl == 0 && j < N_LAB) acc += logsig(p);
    }

    // ---- wave reduce (group leaders) then block reduce -> 1 atomic ----
    acc += __shfl_xor(acc, 16);
    acc += __shfl_xor(acc, 32);

    __shared__ float part[4];
    if (lane == 0) part[threadIdx.x >> 6] = acc;
    __syncthreads();
    if (threadIdx.x == 0) {
        const float s = part[0] + part[1] + part[2] + part[3];
        atomicAdd(out, -s);
    }
}

extern "C" void kernel_launch(void* const* d_in, const int* in_sizes, int n_in,
                              void* d_out, int out_size, void* d_ws, size_t ws_size,
                              hipStream_t stream) {
    const int*   input      = (const int*)  d_in[0];
    const int*   pos_labels = (const int*)  d_in[1];
    const int*   neg_labels = (const int*)  d_in[2];
    const float* input_emb  = (const float*)d_in[3];
    const float* output_emb = (const float*)d_in[4];
    float*       out        = (float*)      d_out;

    // d_out is poisoned (0xAA) and not re-zeroed between replays.
    hipMemsetAsync(out, 0, sizeof(float), stream);

    // 4096 blocks x 256 threads = 16384 waves -> exactly 1 element per wave.
    dim3 grid(4096), block(256);
    hipLaunchKernelGGL(skipgram_kernel, grid, block, 0, stream,
                       input, pos_labels, neg_labels, input_emb, output_emb, out);
}

// Round 5
// 91.973 us; speedup vs baseline: 2.6210x; 1.0731x over previous
//
#include <hip/hip_runtime.h>

// SkipGram negative-sampling loss on MI355X — round 5.
// R4 structure, pipeline depth 4 -> 8: cover ~770cy of compute between
// row-load issue and consume (matches L2-miss/L3-hit latency).

#define VOCAB  100000
#define EMB    128
#define B_TOT  16384
#define W_POS  10
#define K_NEG  64
#define N_LAB  (W_POS + K_NEG)   // 74
#define NCHUNK 19                // ceil(74/4)
#define DEPTH  8                 // row-load pipeline depth

__device__ __forceinline__ float logsig(float x) {
    // log_sigmoid(x) = min(x,0) - log1p(exp(-|x|)); hw exp/log only.
    const float e = __expf(-fabsf(x));
    return fminf(x, 0.0f) - 0.69314718056f * __log2f(1.0f + e);
}

__global__ __launch_bounds__(256, 4) void skipgram_kernel(
    const int*   __restrict__ input,       // [B]
    const int*   __restrict__ pos_labels,  // [B, W_POS]
    const int*   __restrict__ neg_labels,  // [B, K_NEG]
    const float* __restrict__ input_emb,   // [VOCAB, EMB]
    const float* __restrict__ output_emb,  // [VOCAB, EMB]
    float*       __restrict__ out)         // [1]
{
    const int lane = threadIdx.x & 63;
    const int gl   = lane & 15;   // lane within 16-lane group
    const int grp  = lane >> 4;   // which label of each 4-label chunk
    const int wave = (int)((blockIdx.x * blockDim.x + threadIdx.x) >> 6);
    const int b    = wave;        // one element per wave, grid sized exactly

    const int* pl = pos_labels + b * W_POS;
    const int* nl = neg_labels + b * K_NEG;

    // ---- all index loads up front (independent, all in flight) ----
    int idx[NCHUNK];
    #pragma unroll
    for (int t = 0; t < NCHUNK; ++t) {
        const int j = 4 * t + grp;
        idx[t] = (j < W_POS) ? pl[j] : ((j < N_LAB) ? nl[j - W_POS] : 0);
    }

    // ---- center row ----
    const int c = input[b];
    const float4* crow = (const float4*)(input_emb + (size_t)c * EMB);
    const float4 c0 = crow[gl * 2], c1 = crow[gl * 2 + 1];

    // ---- depth-8 pipelined row gathers ----
    float4 A[DEPTH][2];
    #pragma unroll
    for (int t = 0; t < DEPTH; ++t) {
        const float4* rp = (const float4*)(output_emb + (size_t)idx[t] * EMB);
        A[t][0] = rp[gl * 2];
        A[t][1] = rp[gl * 2 + 1];
    }

    float acc = 0.0f;

    #pragma unroll
    for (int t = 0; t < NCHUNK; ++t) {
        const float4 a0 = A[t % DEPTH][0];
        const float4 a1 = A[t % DEPTH][1];

        // refill this slot with chunk t+DEPTH (static index after unroll)
        if (t + DEPTH < NCHUNK) {
            const float4* rp =
                (const float4*)(output_emb + (size_t)idx[t + DEPTH] * EMB);
            A[t % DEPTH][0] = rp[gl * 2];
            A[t % DEPTH][1] = rp[gl * 2 + 1];
        }

        float p = a0.x * c0.x + a0.y * c0.y + a0.z * c0.z + a0.w * c0.w
                + a1.x * c1.x + a1.y * c1.y + a1.z * c1.z + a1.w * c1.w;

        p += __shfl_xor(p, 1);
        p += __shfl_xor(p, 2);
        p += __shfl_xor(p, 4);
        p += __shfl_xor(p, 8);

        const int j = 4 * t + grp;
        if (gl == 0 && j < N_LAB) acc += logsig(p);
    }

    // ---- wave reduce (group leaders) then block reduce -> 1 atomic ----
    acc += __shfl_xor(acc, 16);
    acc += __shfl_xor(acc, 32);

    __shared__ float part[4];
    if (lane == 0) part[threadIdx.x >> 6] = acc;
    __syncthreads();
    if (threadIdx.x == 0) {
        const float s = part[0] + part[1] + part[2] + part[3];
        atomicAdd(out, -s);
    }
}

extern "C" void kernel_launch(void* const* d_in, const int* in_sizes, int n_in,
                              void* d_out, int out_size, void* d_ws, size_t ws_size,
                              hipStream_t stream) {
    const int*   input      = (const int*)  d_in[0];
    const int*   pos_labels = (const int*)  d_in[1];
    const int*   neg_labels = (const int*)  d_in[2];
    const float* input_emb  = (const float*)d_in[3];
    const float* output_emb = (const float*)d_in[4];
    float*       out        = (float*)      d_out;

    // d_out is poisoned (0xAA) and not re-zeroed between replays.
    hipMemsetAsync(out, 0, sizeof(float), stream);

    // 4096 blocks x 256 threads = 16384 waves -> exactly 1 element per wave.
    dim3 grid(4096), block(256);
    hipLaunchKernelGGL(skipgram_kernel, grid, block, 0, stream,
                       input, pos_labels, neg_labels, input_emb, output_emb, out);
}